// Round 8
// baseline (85.702 us; speedup 1.0000x reference)
//
#include <hip/hip_runtime.h>

// DynamicDifferentiablePalette: per-pixel softmax-weighted palette blend.
// images [16,256,256,3] f32, palettes [16,64,3] f32, palette_sizes [16] i32,
// temperature f32 -> out [16,256,256,3] f32.
//
// Round-7: coefficient fetch moved to the SCALAR pipe by construction.
//  - softmax shift-invariance: logit = (2 p.x - ||p||^2 - 3)/T, scaled by
//    log2(e) so weight = exp2f(l) = one v_exp_f32; args bounded [-8.7, 4.4].
//  - coef quad {a0,a1,a2,c} per (b,k), a = 2*log2e/T * p. Blend accumulates
//    Sum(w*a) and divides by 2*log2e/T at the end -> only 16 B per k.
//  - coefs staged in __constant__ (addrspace 4) via d_ws + hipMemcpyAsync D2D:
//    uniform-index reads are s_load_dwordx4 (K$, scalar pipe) -- rounds 4/6
//    were LDS-issue-bound / VMEM-L1-bound on this same fetch.

#define BATCH 16
#define HW 65536
#define KMAX 64
#define BLOCKS_PER_IMG 256
#define CF_ELEMS (BATCH * KMAX * 4)

__constant__ float cf_const[CF_ELEMS];

__global__ __launch_bounds__(64) void coef_kernel(
    const float* __restrict__ palettes,
    const float* __restrict__ temperature,
    float*       __restrict__ cf)
{
    const int b = blockIdx.x;
    const int k = threadIdx.x;
    const float scale = 1.4426950408889634f / temperature[0];   // log2(e)/T

    const float pr = palettes[(b * KMAX + k) * 3 + 0];
    const float pg = palettes[(b * KMAX + k) * 3 + 1];
    const float pb = palettes[(b * KMAX + k) * 3 + 2];

    float* o = cf + ((b * KMAX + k) << 2);
    o[0] = 2.0f * pr * scale;
    o[1] = 2.0f * pg * scale;
    o[2] = 2.0f * pb * scale;
    o[3] = (-(pr * pr + pg * pg + pb * pb) - 3.0f) * scale;  // -3/T shift for exp2 range
}

__global__ __launch_bounds__(256) void palette_blend_kernel(
    const float* __restrict__ images,
    const int*   __restrict__ palette_sizes,
    const float* __restrict__ temperature,
    float*       __restrict__ out)
{
    const int b   = blockIdx.x >> 8;
    const int pix = ((blockIdx.x & (BLOCKS_PER_IMG - 1)) << 8) + threadIdx.x;
    const int K   = palette_sizes[b];

    const long base = (long)b * (HW * 3) + (long)pix * 3;
    const float x0 = images[base + 0];
    const float x1 = images[base + 1];
    const float x2 = images[base + 2];

    const int cbase = (b * KMAX) << 2;   // uniform

    float s = 0.0f, o0 = 0.0f, o1 = 0.0f, o2 = 0.0f;
    #pragma unroll 4
    for (int k = 0; k < K; ++k) {
        // uniform index into __constant__ -> s_load_dwordx4
        const float a0 = cf_const[cbase + (k << 2) + 0];
        const float a1 = cf_const[cbase + (k << 2) + 1];
        const float a2 = cf_const[cbase + (k << 2) + 2];
        const float c  = cf_const[cbase + (k << 2) + 3];
        const float l  = fmaf(a0, x0, fmaf(a1, x1, fmaf(a2, x2, c)));
        const float w  = exp2f(l);
        s  += w;
        o0 = fmaf(w, a0, o0);            // Sum(w * a) = 2*scale * Sum(w * p)
        o1 = fmaf(w, a1, o1);
        o2 = fmaf(w, a2, o2);
    }

    const float scale = 1.4426950408889634f / temperature[0];
    const float inv   = 1.0f / (s * 2.0f * scale);   // undo the a = 2*scale*p factor
    out[base + 0] = o0 * inv;
    out[base + 1] = o1 * inv;
    out[base + 2] = o2 * inv;
}

extern "C" void kernel_launch(void* const* d_in, const int* in_sizes, int n_in,
                              void* d_out, int out_size, void* d_ws, size_t ws_size,
                              hipStream_t stream) {
    const float* images        = (const float*)d_in[0];
    const float* palettes      = (const float*)d_in[1];
    const int*   palette_sizes = (const int*)d_in[2];
    const float* temperature   = (const float*)d_in[3];
    float*       out           = (float*)d_out;
    float*       cf            = (float*)d_ws;   // 16 KB staging

    void* sym = nullptr;
    (void)hipGetSymbolAddress(&sym, HIP_SYMBOL(cf_const));  // not a stream op; capture-safe

    coef_kernel<<<dim3(BATCH), dim3(KMAX), 0, stream>>>(palettes, temperature, cf);
    (void)hipMemcpyAsync(sym, cf, CF_ELEMS * sizeof(float),
                         hipMemcpyDeviceToDevice, stream);
    palette_blend_kernel<<<dim3(BATCH * BLOCKS_PER_IMG), dim3(256), 0, stream>>>(
        images, palette_sizes, temperature, out);
}

// Round 9
// 84.993 us; speedup vs baseline: 1.0083x; 1.0083x over previous
//
#include <hip/hip_runtime.h>

// DynamicDifferentiablePalette: per-pixel softmax-weighted palette blend.
// images [16,256,256,3] f32, palettes [16,64,3] f32, palette_sizes [16] i32,
// temperature f32 -> out [16,256,256,3] f32.
//
// Round-9: 4 pixels per thread to amortize the per-k coefficient fetch.
//  Rounds 6 vs 8 (VMEM float4 vs __constant__ s_load) timed IDENTICALLY ->
//  bottleneck is per-k issue slots, not the fetch pipe. Now each k does
//  1 coefficient float4 load + 4 pixels x 9 VALU (vs 1 fetch per 8 VALU).
//  Image I/O fully vectorized: 3x dwordx4 load + 3x dwordx4 store per thread.
//  Math: logit = (2 p.x - ||p||^2 - 3) * log2e/T; w = exp2f(l) (one v_exp_f32,
//  args in [-8.7, 4.4] for T=1, inputs in [0,1]); accumulate Sum(w*a) with
//  a = 2*log2e/T*p and divide by 2*log2e/T once at the end.

#define BATCH 16
#define HW 65536
#define KMAX 64
#define PX_PER_THREAD 4
#define BLOCKS_PER_IMG 64   // 65536 / (256 threads * 4 px)

__global__ __launch_bounds__(64) void coef_kernel(
    const float* __restrict__ palettes,
    const float* __restrict__ temperature,
    float4*      __restrict__ cf)
{
    const int b = blockIdx.x;
    const int k = threadIdx.x;
    const float scale = 1.4426950408889634f / temperature[0];   // log2(e)/T

    const float pr = palettes[(b * KMAX + k) * 3 + 0];
    const float pg = palettes[(b * KMAX + k) * 3 + 1];
    const float pb = palettes[(b * KMAX + k) * 3 + 2];

    float4 q;
    q.x = 2.0f * pr * scale;
    q.y = 2.0f * pg * scale;
    q.z = 2.0f * pb * scale;
    q.w = (-(pr * pr + pg * pg + pb * pb) - 3.0f) * scale;  // -3/T shift for exp2 range
    cf[b * KMAX + k] = q;
}

__global__ __launch_bounds__(256) void palette_blend_kernel(
    const float* __restrict__ images,
    const int*   __restrict__ palette_sizes,
    const float* __restrict__ temperature,
    const float4* __restrict__ cf,
    float*       __restrict__ out)
{
    const int b    = blockIdx.x >> 6;                       // image
    const int blk  = blockIdx.x & (BLOCKS_PER_IMG - 1);
    const int pix0 = (blk << 10) + (threadIdx.x << 2);      // first of 4 pixels
    const int K    = palette_sizes[b];

    const long base = (long)b * (HW * 3) + (long)pix0 * 3;  // 48B-aligned
    const float4 v0 = *(const float4*)(images + base + 0);
    const float4 v1 = *(const float4*)(images + base + 4);
    const float4 v2 = *(const float4*)(images + base + 8);

    // pixel components (RGB interleaved across the 3 float4s)
    const float xA0 = v0.x, xA1 = v0.y, xA2 = v0.z;
    const float xB0 = v0.w, xB1 = v1.x, xB2 = v1.y;
    const float xC0 = v1.z, xC1 = v1.w, xC2 = v2.x;
    const float xD0 = v2.y, xD1 = v2.z, xD2 = v2.w;

    const float4* __restrict__ c4 = cf + b * KMAX;          // wave-uniform

    float sA = 0.f, aA0 = 0.f, aA1 = 0.f, aA2 = 0.f;
    float sB = 0.f, aB0 = 0.f, aB1 = 0.f, aB2 = 0.f;
    float sC = 0.f, aC0 = 0.f, aC1 = 0.f, aC2 = 0.f;
    float sD = 0.f, aD0 = 0.f, aD1 = 0.f, aD2 = 0.f;

    #pragma unroll 2
    for (int k = 0; k < K; ++k) {
        const float4 A = c4[k];   // {a0,a1,a2,c} — one 16B fetch for 4 pixels
        const float lA = fmaf(A.x, xA0, fmaf(A.y, xA1, fmaf(A.z, xA2, A.w)));
        const float lB = fmaf(A.x, xB0, fmaf(A.y, xB1, fmaf(A.z, xB2, A.w)));
        const float lC = fmaf(A.x, xC0, fmaf(A.y, xC1, fmaf(A.z, xC2, A.w)));
        const float lD = fmaf(A.x, xD0, fmaf(A.y, xD1, fmaf(A.z, xD2, A.w)));
        const float wA = exp2f(lA), wB = exp2f(lB), wC = exp2f(lC), wD = exp2f(lD);
        sA += wA; aA0 = fmaf(wA, A.x, aA0); aA1 = fmaf(wA, A.y, aA1); aA2 = fmaf(wA, A.z, aA2);
        sB += wB; aB0 = fmaf(wB, A.x, aB0); aB1 = fmaf(wB, A.y, aB1); aB2 = fmaf(wB, A.z, aB2);
        sC += wC; aC0 = fmaf(wC, A.x, aC0); aC1 = fmaf(wC, A.y, aC1); aC2 = fmaf(wC, A.z, aC2);
        sD += wD; aD0 = fmaf(wD, A.x, aD0); aD1 = fmaf(wD, A.y, aD1); aD2 = fmaf(wD, A.z, aD2);
    }

    const float scale = 1.4426950408889634f / temperature[0];
    const float h = 0.5f / scale;                 // undo a = 2*scale*p
    const float iA = h / sA, iB = h / sB, iC = h / sC, iD = h / sD;

    float4 o0, o1, o2;
    o0.x = aA0 * iA; o0.y = aA1 * iA; o0.z = aA2 * iA;
    o0.w = aB0 * iB; o1.x = aB1 * iB; o1.y = aB2 * iB;
    o1.z = aC0 * iC; o1.w = aC1 * iC; o2.x = aC2 * iC;
    o2.y = aD0 * iD; o2.z = aD1 * iD; o2.w = aD2 * iD;

    *(float4*)(out + base + 0) = o0;
    *(float4*)(out + base + 4) = o1;
    *(float4*)(out + base + 8) = o2;
}

extern "C" void kernel_launch(void* const* d_in, const int* in_sizes, int n_in,
                              void* d_out, int out_size, void* d_ws, size_t ws_size,
                              hipStream_t stream) {
    const float* images        = (const float*)d_in[0];
    const float* palettes      = (const float*)d_in[1];
    const int*   palette_sizes = (const int*)d_in[2];
    const float* temperature   = (const float*)d_in[3];
    float*       out           = (float*)d_out;
    float4*      cf            = (float4*)d_ws;   // 16 KB

    coef_kernel<<<dim3(BATCH), dim3(KMAX), 0, stream>>>(palettes, temperature, cf);
    palette_blend_kernel<<<dim3(BATCH * BLOCKS_PER_IMG), dim3(256), 0, stream>>>(
        images, palette_sizes, temperature, cf, out);
}